// Round 8
// baseline (3444.804 us; speedup 1.0000x reference)
//
#include <hip/hip_runtime.h>

#define HB 16
#define HN 4096
#define HS 1024
#define HK 32
#define HC 128
#define NCOL (HB*HS*HK)   // 524288

typedef _Float16 half8  __attribute__((ext_vector_type(8)));
typedef _Float16 half4v __attribute__((ext_vector_type(4)));
typedef float    f32x4  __attribute__((ext_vector_type(4)));
typedef float    f32x2  __attribute__((ext_vector_type(2)));
typedef unsigned long long u64;

// ---- workspace offsets (bytes) ----
#define WS_STATS   0u          // sum1,sq1,sum2,sq2 (128 ea), sum3,sq3 (256 ea) = 4096 B
#define WS_BN      4096u       // A1h..B2h halves (1024B); a3f,b3f floats (2048B); counters @+3072
#define WS_CTR     7168u       // 3 x u32 done-counters (zeroed by memset)
#define WS_A1H     8192u       // half [128][160]
#define WS_A2H     49152u      // half [128][128]
#define WS_A3H     81920u      // half [256][128]
#define WS_XYZPP   147456u     // float4 [16][4096]
#define WS_GIDX    1196032u    // int [16][1024][32]
#define WS_FEATT   3293184u    // half [16][4096][128]
#define WS_Y1      20070400u   // half [524288][128]  (knn keybuf before conv1; y2 in place)

// =====================================================================
// Head kernel (256 threads/block) — FPS part is the measured-best r5 code
// =====================================================================
__global__ __launch_bounds__(256) void head_kernel(
    const float* __restrict__ xyz, const float* __restrict__ features,
    const float* __restrict__ w1, const float* __restrict__ w2, const float* __restrict__ w3,
    _Float16* __restrict__ a1h, _Float16* __restrict__ a2h, _Float16* __restrict__ a3h,
    _Float16* __restrict__ featt, float4* __restrict__ xyzpp, float* __restrict__ out)
{
#pragma clang fp contract(off)
  __shared__ union {
    float tbuf[64][65];                       // 16.6 KB transpose tile
    struct {                                  // 49.2 KB FPS state
      float xyzt[HN*3];                       // xyz table (exact input bits)
      unsigned long long K[2][4];             // cross-wave keys (dbuf)
    } fps;
  } lds;
  const int bid = blockIdx.x;
  const int t = threadIdx.x;

  if (bid < 16) {
    // ---------------- FPS: bit-exact vs numpy reference ----------------
    const int b = bid;
    const float* xb = xyz + (size_t)b*HN*3;
    f32x2 pX[8], pY[8], pZ[8], dm[8];
    #pragma unroll
    for (int h = 0; h < 8; ++h) {
      #pragma unroll
      for (int e = 0; e < 2; ++e) {
        int n = t*16 + h*2 + e;
        float x = xb[n*3+0], y = xb[n*3+1], z = xb[n*3+2];
        pX[h][e] = x; pY[h][e] = y; pZ[h][e] = z;
        lds.fps.xyzt[n*3+0] = x; lds.fps.xyzt[n*3+1] = y; lds.fps.xyzt[n*3+2] = z;
      }
      dm[h] = f32x2{1e10f, 1e10f};
    }
    float cx = xb[0], cy = xb[1], cz = xb[2];
    float sc[4][3];
    #pragma unroll
    for (int k = 0; k < 4; ++k) { sc[k][0]=0.0f; sc[k][1]=0.0f; sc[k][2]=0.0f; }
    if (t == 0) { out[(size_t)(b*HS)*3+0] = cx; out[(size_t)(b*HS)*3+1] = cy; out[(size_t)(b*HS)*3+2] = cz; }
    const int wv = t >> 6, l = t & 63;

    for (int i = 1; i < HS; ++i) {
      // ---- packed distance update (IEEE-identical per lane, contract off) ----
      f32x2 vcx = {cx, cx}, vcy = {cy, cy}, vcz = {cz, cz};
      float pm[8];
      #pragma unroll
      for (int h = 0; h < 8; ++h) {
        f32x2 dx = pX[h] - vcx, dy = pY[h] - vcy, dz = pZ[h] - vcz;
        f32x2 d = ((dx*dx) + (dy*dy)) + (dz*dz);      // matches np sum order
        f32x2 nd = __builtin_elementwise_min(dm[h], d);
        dm[h] = nd;
        pm[h] = fmaxf(nd[0], nd[1]);
      }
      // ---- thread max via fmax tree ----
      float q0 = fmaxf(pm[0], pm[1]), q1 = fmaxf(pm[2], pm[3]);
      float q2 = fmaxf(pm[4], pm[5]), q3 = fmaxf(pm[6], pm[7]);
      float mymax = fmaxf(fmaxf(q0, q1), fmaxf(q2, q3));
      // ---- wave max via DPP (register-speed) ----
      int xk = __float_as_int(mymax);
      #define WMAXSTEP(ctrl) { int o_ = __builtin_amdgcn_update_dpp(xk, xk, ctrl, 0xF, 0xF, false); \
        xk = __float_as_int(fmaxf(__int_as_float(xk), __int_as_float(o_))); }
      WMAXSTEP(0x111)  // row_shr:1
      WMAXSTEP(0x112)  // row_shr:2
      WMAXSTEP(0x114)  // row_shr:4
      WMAXSTEP(0x118)  // row_shr:8
      WMAXSTEP(0x142)  // row_bcast:15
      WMAXSTEP(0x143)  // row_bcast:31
      #undef WMAXSTEP
      float wmax = __int_as_float(__builtin_amdgcn_readlane(xk, 63));
      unsigned long long msk = __ballot(mymax == wmax);
      int winl = __ffsll(msk) - 1;              // lowest lane = lowest point index
      // ---- first j in this thread equal to wmax (priority select, shallow) ----
      int j = 0;
      #pragma unroll
      for (int h = 7; h >= 0; --h) {
        int e = (dm[h][0] == wmax) ? 0 : 1;
        if (pm[h] == wmax) j = 2*h + e;          // descending h: smallest h wins
      }
      int n_cand = t*16 + j;
      int n_w = __builtin_amdgcn_readlane(n_cand, winl);

      const int p = i & 1;
      if (l == 0) {
        lds.fps.K[p][wv] = ((unsigned long long)__float_as_uint(wmax) << 32)
                         | (unsigned int)(HN-1 - n_w);
      }
      __syncthreads();                           // no pending vmem -> cheap drain
      unsigned long long k0 = lds.fps.K[p][0], k1 = lds.fps.K[p][1];
      unsigned long long k2 = lds.fps.K[p][2], k3 = lds.fps.K[p][3];
      unsigned long long ka = (k0 >= k1) ? k0 : k1;
      unsigned long long kb = (k2 >= k3) ? k2 : k3;
      unsigned long long kk = (ka >= kb) ? ka : kb;
      int n_best = HN-1 - (int)(unsigned int)(kk & 0xFFFFFFFFull);
      int off = n_best*3;
      cx = lds.fps.xyzt[off+0];                  // broadcast ds_read (exact bits)
      cy = lds.fps.xyzt[off+1];
      cz = lds.fps.xyzt[off+2];
      if ((i & 255) == t) {                      // defer store to registers
        int s = i >> 8;
        #pragma unroll
        for (int k = 0; k < 4; ++k)
          if (s == k) { sc[k][0] = cx; sc[k][1] = cy; sc[k][2] = cz; }
      }
    }
    // ---- post-loop: coalesced new_xyz stores ----
    #pragma unroll
    for (int k = 0; k < 4; ++k) {
      int i = k*256 + t;
      if (i >= 1) {
        size_t o3 = (size_t)(b*HS + i)*3;
        out[o3+0] = sc[k][0]; out[o3+1] = sc[k][1]; out[o3+2] = sc[k][2];
      }
    }
  } else if (bid < 16 + 1024) {
    // -------- feature transpose [B,C,N]f32 -> [B,N,C]fp16, 2 channel-halves --------
    const int tb = bid - 16;
    const int bb = tb >> 6, n0 = (tb & 63) * 64;
    const int wvv = t >> 6, lane = t & 63;       // 4 waves
    for (int h = 0; h < 2; ++h) {
      #pragma unroll
      for (int rep = 0; rep < 16; ++rep) {
        int cc = rep*4 + wvv;
        lds.tbuf[cc][lane] = features[((size_t)(bb*HC + h*64 + cc))*HN + n0 + lane];
      }
      __syncthreads();
      #pragma unroll
      for (int rep = 0; rep < 2; ++rep) {
        int item = rep*256 + t;
        int n = item >> 3, cg = (item & 7) * 8;
        half8 v;
        #pragma unroll
        for (int j = 0; j < 8; ++j) v[j] = (_Float16)lds.tbuf[cg + j][n];
        *(half8*)(featt + ((size_t)(bb*HN) + n0 + n) * HC + h*64 + cg) = v;
      }
      __syncthreads();
    }
  } else if (bid < 16 + 1024 + 256) {
    // ---------------- xyzpp table ----------------
    int gi = (bid - 1040)*256 + t;
    const float* p = xyz + (size_t)gi*3;
    float x = p[0], y = p[1], z = p[2];
    float pp = ((x*x) + (y*y)) + (z*z);
    xyzpp[gi] = make_float4(x, y, z, pp);
  } else {
    // ---------------- weight repack to fp16 ----------------
    int wi = (bid - 1296)*256 + t;
    if (wi < 20480) {
      int o = wi / 160, c = wi - o*160;
      float v = 0.0f;
      if (c < 128) v = w1[o*131 + 3 + c];        // feature part
      else if (c < 131) v = w1[o*131 + (c-128)]; // gxn part
      a1h[wi] = (_Float16)v;
    } else if (wi < 20480 + 16384) {
      a2h[wi - 20480] = (_Float16)w2[wi - 20480];
    } else if (wi < 20480 + 16384 + 32768) {
      a3h[wi - 36864] = (_Float16)w3[wi - 36864];
    }
  }
}

// =====================================================================
// KNN phase 1: 8 shards/batch; per-thread FIFO + bitonic flush over 512 pts
// =====================================================================
#define LEXLT(d1,i1,d2,i2) ((d1) < (d2) || ((d1) == (d2) && (i1) < (i2)))

__global__ __launch_bounds__(64) void knn_p1(
    const float* __restrict__ newxyz, const float4* __restrict__ xyzpp, u64* __restrict__ keybuf)
{
#pragma clang fp contract(off)
  const int t = threadIdx.x;
  const int blk = blockIdx.x;
  const int b = blk >> 7, rem = blk & 127;
  const int shard = rem >> 4, qg = rem & 15;
  const int q = b*1024 + qg*64 + t;
  float qx = newxyz[(size_t)q*3+0], qy = newxyz[(size_t)q*3+1], qz = newxyz[(size_t)q*3+2];
  float qq = ((qx*qx) + (qy*qy)) + (qz*qz);

  const float INF = __builtin_inff();
  float td[32]; int ti[32];
  #pragma unroll
  for (int j = 0; j < 32; ++j) { td[j] = INF; ti[j] = 0x7FFFFFFF; }
  float root = INF;
  int cnt = 0;

  __shared__ float fdl[32][64];
  __shared__ int   fil[32][64];
  const float4* P = xyzpp + (size_t)b*HN + shard*512;

  auto flush = [&]() {
    float gd[32]; int gi2[32];
    #pragma unroll
    for (int j = 0; j < 32; ++j) {
      gd[j] = fdl[j][t]; gi2[j] = fil[j][t];
      if (j >= cnt) { gd[j] = INF; gi2[j] = 0x7FFFFFFF; }
    }
    cnt = 0;
    #pragma unroll
    for (int k = 2; k <= 32; k <<= 1) {
      #pragma unroll
      for (int j = k >> 1; j > 0; j >>= 1) {
        #pragma unroll
        for (int i = 0; i < 32; ++i) {
          int l = i ^ j;
          if (l > i) {
            bool up = ((i & k) == 0);
            bool sw = up ? LEXLT(gd[l], gi2[l], gd[i], gi2[i])
                         : LEXLT(gd[i], gi2[i], gd[l], gi2[l]);
            if (sw) { float tf = gd[i]; gd[i] = gd[l]; gd[l] = tf;
                      int   ii = gi2[i]; gi2[i] = gi2[l]; gi2[l] = ii; }
          }
        }
      }
    }
    #pragma unroll
    for (int i = 0; i < 32; ++i) {
      float od = gd[31-i]; int oi = gi2[31-i];
      if (LEXLT(od, oi, td[i], ti[i])) { td[i] = od; ti[i] = oi; }
    }
    #pragma unroll
    for (int j = 16; j > 0; j >>= 1) {
      #pragma unroll
      for (int i = 0; i < 32; ++i) {
        if ((i & j) == 0) {
          int l = i | j;
          if (LEXLT(td[l], ti[l], td[i], ti[i])) {
            float tf = td[i]; td[i] = td[l]; td[l] = tf;
            int   ii = ti[i]; ti[i] = ti[l]; ti[l] = ii;
          }
        }
      }
    }
    root = td[31];
  };

  for (int n0 = 0; n0 < 512; n0 += 8) {
    float4 pb[8];
    #pragma unroll
    for (int j = 0; j < 8; ++j) pb[j] = P[n0 + j];
    #pragma unroll
    for (int j = 0; j < 8; ++j) {
      float d = (qq + pb[j].w) - 2.0f*(((qx*pb[j].x) + (qy*pb[j].y)) + (qz*pb[j].z));
      if (d < root) { fdl[cnt][t] = d; fil[cnt][t] = shard*512 + n0 + j; cnt++; }
    }
    if (__ballot(cnt > 24)) flush();
  }
  if (__ballot(cnt > 0)) flush();

  // sortable u64 keys: (order-preserving f32 map << 32) | idx
  const size_t base = (size_t)(b*16 + qg) * 16384 + (size_t)shard * 2048;
  #pragma unroll
  for (int j = 0; j < 32; ++j) {
    unsigned bits = __float_as_uint(td[j]);
    unsigned s = bits ^ (((unsigned)((int)bits >> 31)) | 0x80000000u);
    keybuf[base + (size_t)j*64 + t] = ((u64)s << 32) | (unsigned)ti[j];
  }
}

// =====================================================================
// KNN phase 2: merge 8 shard-lists (8x32 keys) per query -> top-32 indices
// =====================================================================
__global__ __launch_bounds__(64) void knn_p2(const u64* __restrict__ keybuf, int* __restrict__ gidx)
{
  const int t = threadIdx.x;
  const int g = blockIdx.x;                 // (b*16 + qg)
  const size_t base = (size_t)g * 16384;

  u64 tk[32];
  #pragma unroll
  for (int j = 0; j < 32; ++j) tk[j] = ~0ULL;
  u64 root = ~0ULL;
  int cnt = 0;
  __shared__ u64 fk[32][64];

  auto flush64 = [&]() {
    u64 gd[32];
    #pragma unroll
    for (int j = 0; j < 32; ++j) {
      gd[j] = fk[j][t];
      if (j >= cnt) gd[j] = ~0ULL;
    }
    cnt = 0;
    #pragma unroll
    for (int k = 2; k <= 32; k <<= 1) {
      #pragma unroll
      for (int j = k >> 1; j > 0; j >>= 1) {
        #pragma unroll
        for (int i = 0; i < 32; ++i) {
          int l = i ^ j;
          if (l > i) {
            bool up = ((i & k) == 0);
            bool sw = up ? (gd[l] < gd[i]) : (gd[i] < gd[l]);
            if (sw) { u64 tf = gd[i]; gd[i] = gd[l]; gd[l] = tf; }
          }
        }
      }
    }
    #pragma unroll
    for (int i = 0; i < 32; ++i) {
      u64 od = gd[31-i];
      if (od < tk[i]) tk[i] = od;
    }
    #pragma unroll
    for (int j = 16; j > 0; j >>= 1) {
      #pragma unroll
      for (int i = 0; i < 32; ++i) {
        if ((i & j) == 0) {
          int l = i | j;
          if (tk[l] < tk[i]) { u64 tf = tk[i]; tk[i] = tk[l]; tk[l] = tf; }
        }
      }
    }
    root = tk[31];
  };

  for (int k0 = 0; k0 < 256; k0 += 8) {
    u64 kk[8];
    #pragma unroll
    for (int j = 0; j < 8; ++j) kk[j] = keybuf[base + (size_t)(k0 + j)*64 + t];
    #pragma unroll
    for (int j = 0; j < 8; ++j) {
      if (kk[j] < root) { fk[cnt][t] = kk[j]; cnt++; }
    }
    if (__ballot(cnt > 24)) flush64();
  }
  if (__ballot(cnt > 0)) flush64();

  const int q = g*64 + t;
  #pragma unroll
  for (int j = 0; j < 32; j += 4) {
    int4 v = { (int)(unsigned)tk[j], (int)(unsigned)tk[j+1], (int)(unsigned)tk[j+2], (int)(unsigned)tk[j+3] };
    *(int4*)(gidx + ((size_t)q << 5) + j) = v;
  }
}

// =====================================================================
// Fused conv+BN(+relu)+stats (+pool for MODE 3) + last-block BN finalize
// 128 cols/block (32/wave), acc[8][2] -> ~150 VGPR -> 3 waves/SIMD
// =====================================================================
template<int MODE>
__global__ __launch_bounds__(256, 3) void conv_kernel(
    const _Float16* __restrict__ A, const _Float16* Bsrc,
    const int* __restrict__ gidx, const float4* __restrict__ xyzpp, const float* __restrict__ newxyz,
    const _Float16* __restrict__ bnA, const _Float16* __restrict__ bnB,
    _Float16* Yout, float* __restrict__ osum, float* __restrict__ osq,
    float* __restrict__ pool,
    const float* __restrict__ gg, const float* __restrict__ be,
    _Float16* Ah, _Float16* Bh, float* Af, float* Bf,
    unsigned* ctr, unsigned total, int C)
{
  const int tid = threadIdx.x;
  const int w = tid >> 6, l = tid & 63, ll = l & 15, lh = l >> 4;
  const int colbase = blockIdx.x * 128 + w * 32;
  const int b = colbase >> 15;
  const int AS = (MODE == 1) ? 160 : 128;
  const _Float16* Ap = A + (MODE == 3 ? (size_t)blockIdx.y * 128 * 128 : 0);

  f32x4 acc[8][2] = {};

  half8 bnAv[4], bnBv[4];
  if constexpr (MODE >= 2) {
    #pragma unroll
    for (int c = 0; c < 4; ++c) {
      int k0 = c*32 + lh*8;
      bnAv[c] = *(const half8*)(bnA + k0);
      bnBv[c] = *(const half8*)(bnB + k0);
    }
  }
  int gidxv[2];
  if constexpr (MODE == 1) {
    #pragma unroll
    for (int nf = 0; nf < 2; ++nf) gidxv[nf] = gidx[colbase + nf*16 + ll];
  }

  const int NCH = (MODE == 1) ? 5 : 4;
  #pragma unroll
  for (int c = 0; c < NCH; ++c) {
    half8 a[8];
    #pragma unroll
    for (int mf = 0; mf < 8; ++mf)
      a[mf] = *(const half8*)(Ap + (size_t)(mf*16 + ll)*AS + c*32 + lh*8);
    half8 bfr[2];
    #pragma unroll
    for (int nf = 0; nf < 2; ++nf) {
      if constexpr (MODE == 1) {
        if (c < 4) {
          bfr[nf] = *(const half8*)(Bsrc + ((size_t)(b*HN + gidxv[nf]))*HC + c*32 + lh*8);
        } else {
          half8 z = {};
          if (lh == 0) {
            float4 pw = xyzpp[b*HN + gidxv[nf]];
            int col = colbase + nf*16 + ll;
            int s = (col >> 5) & (HS-1);
            const float* nx = newxyz + (size_t)(b*HS + s)*3;
            z[0] = (_Float16)(pw.x - nx[0]);
            z[1] = (_Float16)(pw.y - nx[1]);
            z[2] = (_Float16)(pw.z - nx[2]);
          }
          bfr[nf] = z;
        }
      } else {
        half8 v = *(const half8*)(Bsrc + ((size_t)(colbase + nf*16 + ll))*HC + c*32 + lh*8);
        v = v * bnAv[c] + bnBv[c];
        half8 hz = {};
        bfr[nf] = __builtin_elementwise_max(v, hz);
      }
    }
    #pragma unroll
    for (int mf = 0; mf < 8; ++mf)
      #pragma unroll
      for (int nf = 0; nf < 2; ++nf)
        acc[mf][nf] = __builtin_amdgcn_mfma_f32_16x16x32_f16(a[mf], bfr[nf], acc[mf][nf], 0, 0, 0);
  }

  // ---------------- epilogue ----------------
  __shared__ float bsum[128], bsq[128];
  __shared__ unsigned lastf;
  if (tid < 128) { bsum[tid] = 0.0f; bsq[tid] = 0.0f; }
  __syncthreads();

  #pragma unroll
  for (int mf = 0; mf < 8; ++mf) {
    int ch0 = mf*16 + lh*4;
    if constexpr (MODE != 3) {
      #pragma unroll
      for (int nf = 0; nf < 2; ++nf) {
        int col = colbase + nf*16 + ll;
        half4v hv;
        #pragma unroll
        for (int r = 0; r < 4; ++r) hv[r] = (_Float16)acc[mf][nf][r];
        *(half4v*)(Yout + (size_t)col*HC + ch0) = hv;
      }
    } else {
      float mx[4];
      #pragma unroll
      for (int r = 0; r < 4; ++r) mx[r] = fmaxf(acc[mf][0][r], acc[mf][1][r]);
      #pragma unroll
      for (int m = 1; m <= 8; m <<= 1)
        #pragma unroll
        for (int r = 0; r < 4; ++r) mx[r] = fmaxf(mx[r], __shfl_xor(mx[r], m, 64));
      if (ll == 0) {
        int s = (colbase >> 5) & (HS-1);
        int chg = blockIdx.y*128 + ch0;
        #pragma unroll
        for (int r = 0; r < 4; ++r)
          pool[(((size_t)(b*256 + chg + r)) << 10) + s] = mx[r];
      }
    }
    float sv[4] = {0,0,0,0}, qv[4] = {0,0,0,0};
    #pragma unroll
    for (int nf = 0; nf < 2; ++nf)
      #pragma unroll
      for (int r = 0; r < 4; ++r) { float v = acc[mf][nf][r]; sv[r] += v; qv[r] += v*v; }
    #pragma unroll
    for (int m = 1; m <= 8; m <<= 1)
      #pragma unroll
      for (int r = 0; r < 4; ++r) { sv[r] += __shfl_xor(sv[r], m, 64); qv[r] += __shfl_xor(qv[r], m, 64); }
    if (ll == 0) {
      #pragma unroll
      for (int r = 0; r < 4; ++r) { atomicAdd(&bsum[ch0+r], sv[r]); atomicAdd(&bsq[ch0+r], qv[r]); }
    }
  }
  __syncthreads();
  if (tid < 128) {
    int choff = (MODE == 3) ? blockIdx.y*128 : 0;
    atomicAdd(&osum[choff + tid], bsum[tid]);
    atomicAdd(&osq[choff + tid], bsq[tid]);
  }
  // ---------------- fused BN-stat finalize (last block) ----------------
  __threadfence();
  __syncthreads();
  if (tid == 0) lastf = (atomicAdd(ctr, 1u) == total - 1u) ? 1u : 0u;
  __syncthreads();
  if (lastf && tid < C) {
    __threadfence();
    float s  = atomicAdd(&osum[tid], 0.0f);   // coherent read-back
    float sq = atomicAdd(&osq[tid], 0.0f);
    float mean = s  * (1.0f/524288.0f);
    float var  = sq * (1.0f/524288.0f) - mean*mean;
    float a  = gg[tid] * rsqrtf(var + 1e-5f);
    float bb = be[tid] - mean*a;
    if constexpr (MODE != 3) { Ah[tid] = (_Float16)a; Bh[tid] = (_Float16)bb; }
    else                     { Af[tid] = a; Bf[tid] = bb; }
  }
}

// =====================================================================
// Final in-place affine+relu on pooled output (bn3)
// =====================================================================
__global__ __launch_bounds__(256) void final_affine(float* __restrict__ outp,
                                                    const float* __restrict__ Af,
                                                    const float* __restrict__ Bf)
{
  int i = blockIdx.x*256 + threadIdx.x;
  float4 v = ((float4*)outp)[i];
  int ch = ((i << 2) >> 10) & 255;
  float a = Af[ch], bb = Bf[ch];
  v.x = fmaxf(v.x*a + bb, 0.0f);
  v.y = fmaxf(v.y*a + bb, 0.0f);
  v.z = fmaxf(v.z*a + bb, 0.0f);
  v.w = fmaxf(v.w*a + bb, 0.0f);
  ((float4*)outp)[i] = v;
}

// =====================================================================
extern "C" void kernel_launch(void* const* d_in, const int* in_sizes, int n_in,
                              void* d_out, int out_size, void* d_ws, size_t ws_size,
                              hipStream_t stream) {
  const float* xyz      = (const float*)d_in[0];
  const float* features = (const float*)d_in[1];
  const float* w1  = (const float*)d_in[2];
  const float* g1  = (const float*)d_in[3];
  const float* b1v = (const float*)d_in[4];
  const float* w2  = (const float*)d_in[5];
  const float* g2  = (const float*)d_in[6];
  const float* b2v = (const float*)d_in[7];
  const float* w3  = (const float*)d_in[8];
  const float* g3  = (const float*)d_in[9];
  const float* b3v = (const float*)d_in[10];
  float* out = (float*)d_out;
  char* ws = (char*)d_ws;

  float* stats = (float*)(ws + WS_STATS);
  float* sum1 = stats;       float* sq1 = stats + 128;
  float* sum2 = stats + 256; float* sq2 = stats + 384;
  float* sum3 = stats + 512; float* sq3 = stats + 768;
  _Float16* A1h = (_Float16*)(ws + WS_BN);
  _Float16* B1h = A1h + 128;
  _Float16* A2h = A1h + 256;
  _Float16* B2h = A1h + 384;
  float* a3f = (float*)(ws + WS_BN + 1024);
  float* b3f = a3f + 256;
  unsigned* ctr = (unsigned*)(ws + WS_CTR);
  _Float16* a1h = (_Float16*)(ws + WS_A1H);
  _Float16* a2h = (_Float16*)(ws + WS_A2H);
  _Float16* a3h = (_Float16*)(ws + WS_A3H);
  float4* xyzpp = (float4*)(ws + WS_XYZPP);
  int* gidx = (int*)(ws + WS_GIDX);
  _Float16* featt = (_Float16*)(ws + WS_FEATT);
  u64* keybuf = (u64*)(ws + WS_Y1);       // y1 region reused before conv1
  _Float16* y1 = (_Float16*)(ws + WS_Y1);
  _Float16* y2 = y1;   // conv2 output overwrites y1 in place (per-column independence)

  hipMemsetAsync(ws + WS_STATS, 0, 8192, stream);   // stats + BN page + counters

  head_kernel<<<1568, 256, 0, stream>>>(xyz, features, w1, w2, w3,
                                        a1h, a2h, a3h, featt, xyzpp, out);
  knn_p1<<<2048, 64, 0, stream>>>(out, xyzpp, keybuf);
  knn_p2<<<256, 64, 0, stream>>>(keybuf, gidx);

  conv_kernel<1><<<4096, 256, 0, stream>>>(a1h, featt, gidx, xyzpp, out,
                                           nullptr, nullptr, y1, sum1, sq1, nullptr,
                                           g1, b1v, A1h, B1h, nullptr, nullptr,
                                           ctr + 0, 4096u, 128);

  conv_kernel<2><<<4096, 256, 0, stream>>>(a2h, y1, nullptr, nullptr, nullptr,
                                           A1h, B1h, y2, sum2, sq2, nullptr,
                                           g2, b2v, A2h, B2h, nullptr, nullptr,
                                           ctr + 1, 4096u, 128);

  conv_kernel<3><<<dim3(4096, 2), 256, 0, stream>>>(a3h, y2, nullptr, nullptr, nullptr,
                                                    A2h, B2h, nullptr, sum3, sq3, out + 49152,
                                                    g3, b3v, nullptr, nullptr, a3f, b3f,
                                                    ctr + 2, 8192u, 256);

  final_affine<<<4096, 256, 0, stream>>>(out + 49152, a3f, b3f);
}

// Round 9
// 1330.309 us; speedup vs baseline: 2.5895x; 2.5895x over previous
//
#include <hip/hip_runtime.h>

#define HB 16
#define HN 4096
#define HS 1024
#define HK 32
#define HC 128

typedef _Float16 half8  __attribute__((ext_vector_type(8)));
typedef _Float16 half4v __attribute__((ext_vector_type(4)));
typedef float    f32x4  __attribute__((ext_vector_type(4)));
typedef float    f32x2  __attribute__((ext_vector_type(2)));
typedef unsigned long long u64;

// ---- workspace offsets (bytes) ----  total = 154,288,128 B
#define WS_BN      4096u       // A1h,B1h,A2h,B2h halves (1KB); a3f,b3f floats (2KB)
#define WS_A1H     8192u       // half [128][160]
#define WS_A2H     49152u      // half [128][128]
#define WS_A3H     81920u      // half [256][128]
#define WS_XYZPP   147456u     // float4 [16][4096]
#define WS_GIDX    1196032u    // int [16][1024][32]
#define WS_FEATT   3293184u    // half [16][4096][128] (dead after conv1 -> stat partials)
#define WS_Y1      20070400u   // half [524288][128]  (knn keybuf before conv1; y2 in place)

// =====================================================================
// Head kernel (256 threads/block) — FPS is the measured-best r5 code
// =====================================================================
__global__ __launch_bounds__(256) void head_kernel(
    const float* __restrict__ xyz, const float* __restrict__ features,
    const float* __restrict__ w1, const float* __restrict__ w2, const float* __restrict__ w3,
    _Float16* __restrict__ a1h, _Float16* __restrict__ a2h, _Float16* __restrict__ a3h,
    _Float16* __restrict__ featt, float4* __restrict__ xyzpp, float* __restrict__ out)
{
#pragma clang fp contract(off)
  __shared__ union {
    float tbuf[64][65];                       // 16.6 KB transpose tile
    struct {                                  // 49.2 KB FPS state
      float xyzt[HN*3];
      unsigned long long K[2][4];
    } fps;
  } lds;
  const int bid = blockIdx.x;
  const int t = threadIdx.x;

  if (bid < 16) {
    // ---------------- FPS: bit-exact vs numpy reference ----------------
    const int b = bid;
    const float* xb = xyz + (size_t)b*HN*3;
    f32x2 pX[8], pY[8], pZ[8], dm[8];
    #pragma unroll
    for (int h = 0; h < 8; ++h) {
      #pragma unroll
      for (int e = 0; e < 2; ++e) {
        int n = t*16 + h*2 + e;
        float x = xb[n*3+0], y = xb[n*3+1], z = xb[n*3+2];
        pX[h][e] = x; pY[h][e] = y; pZ[h][e] = z;
        lds.fps.xyzt[n*3+0] = x; lds.fps.xyzt[n*3+1] = y; lds.fps.xyzt[n*3+2] = z;
      }
      dm[h] = f32x2{1e10f, 1e10f};
    }
    float cx = xb[0], cy = xb[1], cz = xb[2];
    float sc[4][3];
    #pragma unroll
    for (int k = 0; k < 4; ++k) { sc[k][0]=0.0f; sc[k][1]=0.0f; sc[k][2]=0.0f; }
    if (t == 0) { out[(size_t)(b*HS)*3+0] = cx; out[(size_t)(b*HS)*3+1] = cy; out[(size_t)(b*HS)*3+2] = cz; }
    const int wv = t >> 6, l = t & 63;

    for (int i = 1; i < HS; ++i) {
      f32x2 vcx = {cx, cx}, vcy = {cy, cy}, vcz = {cz, cz};
      float pm[8];
      #pragma unroll
      for (int h = 0; h < 8; ++h) {
        f32x2 dx = pX[h] - vcx, dy = pY[h] - vcy, dz = pZ[h] - vcz;
        f32x2 d = ((dx*dx) + (dy*dy)) + (dz*dz);      // matches np sum order
        f32x2 nd = __builtin_elementwise_min(dm[h], d);
        dm[h] = nd;
        pm[h] = fmaxf(nd[0], nd[1]);
      }
      float q0 = fmaxf(pm[0], pm[1]), q1 = fmaxf(pm[2], pm[3]);
      float q2 = fmaxf(pm[4], pm[5]), q3 = fmaxf(pm[6], pm[7]);
      float mymax = fmaxf(fmaxf(q0, q1), fmaxf(q2, q3));
      int xk = __float_as_int(mymax);
      #define WMAXSTEP(ctrl) { int o_ = __builtin_amdgcn_update_dpp(xk, xk, ctrl, 0xF, 0xF, false); \
        xk = __float_as_int(fmaxf(__int_as_float(xk), __int_as_float(o_))); }
      WMAXSTEP(0x111) WMAXSTEP(0x112) WMAXSTEP(0x114)
      WMAXSTEP(0x118) WMAXSTEP(0x142) WMAXSTEP(0x143)
      #undef WMAXSTEP
      float wmax = __int_as_float(__builtin_amdgcn_readlane(xk, 63));
      unsigned long long msk = __ballot(mymax == wmax);
      int winl = __ffsll(msk) - 1;              // lowest lane = lowest point index
      int j = 0;
      #pragma unroll
      for (int h = 7; h >= 0; --h) {
        int e = (dm[h][0] == wmax) ? 0 : 1;
        if (pm[h] == wmax) j = 2*h + e;          // descending h: smallest h wins
      }
      int n_cand = t*16 + j;
      int n_w = __builtin_amdgcn_readlane(n_cand, winl);

      const int p = i & 1;
      if (l == 0) {
        lds.fps.K[p][wv] = ((unsigned long long)__float_as_uint(wmax) << 32)
                         | (unsigned int)(HN-1 - n_w);
      }
      __syncthreads();
      unsigned long long k0 = lds.fps.K[p][0], k1 = lds.fps.K[p][1];
      unsigned long long k2 = lds.fps.K[p][2], k3 = lds.fps.K[p][3];
      unsigned long long ka = (k0 >= k1) ? k0 : k1;
      unsigned long long kb = (k2 >= k3) ? k2 : k3;
      unsigned long long kk = (ka >= kb) ? ka : kb;
      int n_best = HN-1 - (int)(unsigned int)(kk & 0xFFFFFFFFull);
      int off = n_best*3;
      cx = lds.fps.xyzt[off+0];
      cy = lds.fps.xyzt[off+1];
      cz = lds.fps.xyzt[off+2];
      if ((i & 255) == t) {
        int s = i >> 8;
        #pragma unroll
        for (int k = 0; k < 4; ++k)
          if (s == k) { sc[k][0] = cx; sc[k][1] = cy; sc[k][2] = cz; }
      }
    }
    #pragma unroll
    for (int k = 0; k < 4; ++k) {
      int i = k*256 + t;
      if (i >= 1) {
        size_t o3 = (size_t)(b*HS + i)*3;
        out[o3+0] = sc[k][0]; out[o3+1] = sc[k][1]; out[o3+2] = sc[k][2];
      }
    }
  } else if (bid < 16 + 1024) {
    // -------- feature transpose [B,C,N]f32 -> [B,N,C]fp16 --------
    const int tb = bid - 16;
    const int bb = tb >> 6, n0 = (tb & 63) * 64;
    const int wvv = t >> 6, lane = t & 63;
    for (int h = 0; h < 2; ++h) {
      #pragma unroll
      for (int rep = 0; rep < 16; ++rep) {
        int cc = rep*4 + wvv;
        lds.tbuf[cc][lane] = features[((size_t)(bb*HC + h*64 + cc))*HN + n0 + lane];
      }
      __syncthreads();
      #pragma unroll
      for (int rep = 0; rep < 2; ++rep) {
        int item = rep*256 + t;
        int n = item >> 3, cg = (item & 7) * 8;
        half8 v;
        #pragma unroll
        for (int j = 0; j < 8; ++j) v[j] = (_Float16)lds.tbuf[cg + j][n];
        *(half8*)(featt + ((size_t)(bb*HN) + n0 + n) * HC + h*64 + cg) = v;
      }
      __syncthreads();
    }
  } else if (bid < 16 + 1024 + 256) {
    int gi = (bid - 1040)*256 + t;
    const float* p = xyz + (size_t)gi*3;
    float x = p[0], y = p[1], z = p[2];
    float pp = ((x*x) + (y*y)) + (z*z);
    xyzpp[gi] = make_float4(x, y, z, pp);
  } else {
    int wi = (bid - 1296)*256 + t;
    if (wi < 20480) {
      int o = wi / 160, c = wi - o*160;
      float v = 0.0f;
      if (c < 128) v = w1[o*131 + 3 + c];
      else if (c < 131) v = w1[o*131 + (c-128)];
      a1h[wi] = (_Float16)v;
    } else if (wi < 20480 + 16384) {
      a2h[wi - 20480] = (_Float16)w2[wi - 20480];
    } else if (wi < 20480 + 16384 + 32768) {
      a3h[wi - 36864] = (_Float16)w3[wi - 36864];
    }
  }
}

// =====================================================================
// KNN phase 1: 8 shards/batch
// =====================================================================
#define LEXLT(d1,i1,d2,i2) ((d1) < (d2) || ((d1) == (d2) && (i1) < (i2)))

__global__ __launch_bounds__(64) void knn_p1(
    const float* __restrict__ newxyz, const float4* __restrict__ xyzpp, u64* __restrict__ keybuf)
{
#pragma clang fp contract(off)
  const int t = threadIdx.x;
  const int blk = blockIdx.x;
  const int b = blk >> 7, rem = blk & 127;
  const int shard = rem >> 4, qg = rem & 15;
  const int q = b*1024 + qg*64 + t;
  float qx = newxyz[(size_t)q*3+0], qy = newxyz[(size_t)q*3+1], qz = newxyz[(size_t)q*3+2];
  float qq = ((qx*qx) + (qy*qy)) + (qz*qz);

  const float INF = __builtin_inff();
  float td[32]; int ti[32];
  #pragma unroll
  for (int j = 0; j < 32; ++j) { td[j] = INF; ti[j] = 0x7FFFFFFF; }
  float root = INF;
  int cnt = 0;

  __shared__ float fdl[32][64];
  __shared__ int   fil[32][64];
  const float4* P = xyzpp + (size_t)b*HN + shard*512;

  auto flush = [&]() {
    float gd[32]; int gi2[32];
    #pragma unroll
    for (int j = 0; j < 32; ++j) {
      gd[j] = fdl[j][t]; gi2[j] = fil[j][t];
      if (j >= cnt) { gd[j] = INF; gi2[j] = 0x7FFFFFFF; }
    }
    cnt = 0;
    #pragma unroll
    for (int k = 2; k <= 32; k <<= 1) {
      #pragma unroll
      for (int j = k >> 1; j > 0; j >>= 1) {
        #pragma unroll
        for (int i = 0; i < 32; ++i) {
          int l = i ^ j;
          if (l > i) {
            bool up = ((i & k) == 0);
            bool sw = up ? LEXLT(gd[l], gi2[l], gd[i], gi2[i])
                         : LEXLT(gd[i], gi2[i], gd[l], gi2[l]);
            if (sw) { float tf = gd[i]; gd[i] = gd[l]; gd[l] = tf;
                      int   ii = gi2[i]; gi2[i] = gi2[l]; gi2[l] = ii; }
          }
        }
      }
    }
    #pragma unroll
    for (int i = 0; i < 32; ++i) {
      float od = gd[31-i]; int oi = gi2[31-i];
      if (LEXLT(od, oi, td[i], ti[i])) { td[i] = od; ti[i] = oi; }
    }
    #pragma unroll
    for (int j = 16; j > 0; j >>= 1) {
      #pragma unroll
      for (int i = 0; i < 32; ++i) {
        if ((i & j) == 0) {
          int l = i | j;
          if (LEXLT(td[l], ti[l], td[i], ti[i])) {
            float tf = td[i]; td[i] = td[l]; td[l] = tf;
            int   ii = ti[i]; ti[i] = ti[l]; ti[l] = ii;
          }
        }
      }
    }
    root = td[31];
  };

  for (int n0 = 0; n0 < 512; n0 += 8) {
    float4 pb[8];
    #pragma unroll
    for (int j = 0; j < 8; ++j) pb[j] = P[n0 + j];
    #pragma unroll
    for (int j = 0; j < 8; ++j) {
      float d = (qq + pb[j].w) - 2.0f*(((qx*pb[j].x) + (qy*pb[j].y)) + (qz*pb[j].z));
      if (d < root) { fdl[cnt][t] = d; fil[cnt][t] = shard*512 + n0 + j; cnt++; }
    }
    if (__ballot(cnt > 24)) flush();
  }
  if (__ballot(cnt > 0)) flush();

  const size_t base = (size_t)(b*16 + qg) * 16384 + (size_t)shard * 2048;
  #pragma unroll
  for (int j = 0; j < 32; ++j) {
    unsigned bits = __float_as_uint(td[j]);
    unsigned s = bits ^ (((unsigned)((int)bits >> 31)) | 0x80000000u);
    keybuf[base + (size_t)j*64 + t] = ((u64)s << 32) | (unsigned)ti[j];
  }
}

// =====================================================================
// KNN phase 2: merge 8 shard-lists per query -> top-32 indices
// =====================================================================
__global__ __launch_bounds__(64) void knn_p2(const u64* __restrict__ keybuf, int* __restrict__ gidx)
{
  const int t = threadIdx.x;
  const int g = blockIdx.x;
  const size_t base = (size_t)g * 16384;

  u64 tk[32];
  #pragma unroll
  for (int j = 0; j < 32; ++j) tk[j] = ~0ULL;
  u64 root = ~0ULL;
  int cnt = 0;
  __shared__ u64 fk[32][64];

  auto flush64 = [&]() {
    u64 gd[32];
    #pragma unroll
    for (int j = 0; j < 32; ++j) {
      gd[j] = fk[j][t];
      if (j >= cnt) gd[j] = ~0ULL;
    }
    cnt = 0;
    #pragma unroll
    for (int k = 2; k <= 32; k <<= 1) {
      #pragma unroll
      for (int j = k >> 1; j > 0; j >>= 1) {
        #pragma unroll
        for (int i = 0; i < 32; ++i) {
          int l = i ^ j;
          if (l > i) {
            bool up = ((i & k) == 0);
            bool sw = up ? (gd[l] < gd[i]) : (gd[i] < gd[l]);
            if (sw) { u64 tf = gd[i]; gd[i] = gd[l]; gd[l] = tf; }
          }
        }
      }
    }
    #pragma unroll
    for (int i = 0; i < 32; ++i) {
      u64 od = gd[31-i];
      if (od < tk[i]) tk[i] = od;
    }
    #pragma unroll
    for (int j = 16; j > 0; j >>= 1) {
      #pragma unroll
      for (int i = 0; i < 32; ++i) {
        if ((i & j) == 0) {
          int l = i | j;
          if (tk[l] < tk[i]) { u64 tf = tk[i]; tk[i] = tk[l]; tk[l] = tf; }
        }
      }
    }
    root = tk[31];
  };

  for (int k0 = 0; k0 < 256; k0 += 8) {
    u64 kk[8];
    #pragma unroll
    for (int j = 0; j < 8; ++j) kk[j] = keybuf[base + (size_t)(k0 + j)*64 + t];
    #pragma unroll
    for (int j = 0; j < 8; ++j) {
      if (kk[j] < root) { fk[cnt][t] = kk[j]; cnt++; }
    }
    if (__ballot(cnt > 24)) flush64();
  }
  if (__ballot(cnt > 0)) flush64();

  const int q = g*64 + t;
  #pragma unroll
  for (int j = 0; j < 32; j += 4) {
    int4 v = { (int)(unsigned)tk[j], (int)(unsigned)tk[j+1], (int)(unsigned)tk[j+2], (int)(unsigned)tk[j+3] };
    *(int4*)(gidx + ((size_t)q << 5) + j) = v;
  }
}

// =====================================================================
// Fused conv+BN(+relu)+stats (+pool for MODE 3), fp16 MFMA 16x16x32
// Stats: atomic-free per-block partial store (coalesced 1KB/block)
// =====================================================================
template<int MODE>
__global__ __launch_bounds__(256, 2) void conv_kernel(
    const _Float16* __restrict__ A, const _Float16* Bsrc,
    const int* __restrict__ gidx, const float4* __restrict__ xyzpp, const float* __restrict__ newxyz,
    const _Float16* __restrict__ bnA, const _Float16* __restrict__ bnB,
    _Float16* Yout, float* __restrict__ pstat, float* __restrict__ pool)
{
  const int tid = threadIdx.x;
  const int w = tid >> 6, l = tid & 63, ll = l & 15, lh = l >> 4;
  const int colbase = blockIdx.x * 256 + w * 64;
  const int b = colbase >> 15;
  const int AS = (MODE == 1) ? 160 : 128;
  const _Float16* Ap = A + (MODE == 3 ? (size_t)blockIdx.y * 128 * 128 : 0);

  f32x4 acc[8][4] = {};

  half8 bnAv[4], bnBv[4];
  if constexpr (MODE >= 2) {
    #pragma unroll
    for (int c = 0; c < 4; ++c) {
      int k0 = c*32 + lh*8;
      bnAv[c] = *(const half8*)(bnA + k0);
      bnBv[c] = *(const half8*)(bnB + k0);
    }
  }
  int gidxv[4];
  if constexpr (MODE == 1) {
    #pragma unroll
    for (int nf = 0; nf < 4; ++nf) gidxv[nf] = gidx[colbase + nf*16 + ll];
  }

  const int NCH = (MODE == 1) ? 5 : 4;
  #pragma unroll
  for (int c = 0; c < NCH; ++c) {
    half8 a[8];
    #pragma unroll
    for (int mf = 0; mf < 8; ++mf)
      a[mf] = *(const half8*)(Ap + (size_t)(mf*16 + ll)*AS + c*32 + lh*8);
    half8 bfr[4];
    #pragma unroll
    for (int nf = 0; nf < 4; ++nf) {
      if constexpr (MODE == 1) {
        if (c < 4) {
          bfr[nf] = *(const half8*)(Bsrc + ((size_t)(b*HN + gidxv[nf]))*HC + c*32 + lh*8);
        } else {
          half8 z = {};
          if (lh == 0) {
            float4 pw = xyzpp[b*HN + gidxv[nf]];
            int col = colbase + nf*16 + ll;
            int s = (col >> 5) & (HS-1);
            const float* nx = newxyz + (size_t)(b*HS + s)*3;
            z[0] = (_Float16)(pw.x - nx[0]);
            z[1] = (_Float16)(pw.y - nx[1]);
            z[2] = (_Float16)(pw.z - nx[2]);
          }
          bfr[nf] = z;
        }
      } else {
        half8 v = *(const half8*)(Bsrc + ((size_t)(colbase + nf*16 + ll))*HC + c*32 + lh*8);
        v = v * bnAv[c] + bnBv[c];
        half8 hz = {};
        bfr[nf] = __builtin_elementwise_max(v, hz);
      }
    }
    #pragma unroll
    for (int mf = 0; mf < 8; ++mf)
      #pragma unroll
      for (int nf = 0; nf < 4; ++nf)
        acc[mf][nf] = __builtin_amdgcn_mfma_f32_16x16x32_f16(a[mf], bfr[nf], acc[mf][nf], 0, 0, 0);
  }

  // ---------------- epilogue ----------------
  __shared__ float bsum[128], bsq[128];
  if (tid < 128) { bsum[tid] = 0.0f; bsq[tid] = 0.0f; }
  __syncthreads();

  #pragma unroll
  for (int mf = 0; mf < 8; ++mf) {
    int ch0 = mf*16 + lh*4;
    if constexpr (MODE != 3) {
      #pragma unroll
      for (int nf = 0; nf < 4; ++nf) {
        int col = colbase + nf*16 + ll;
        half4v hv;
        #pragma unroll
        for (int r = 0; r < 4; ++r) hv[r] = (_Float16)acc[mf][nf][r];
        *(half4v*)(Yout + (size_t)col*HC + ch0) = hv;
      }
    } else {
      #pragma unroll
      for (int g = 0; g < 2; ++g) {
        float mx[4];
        #pragma unroll
        for (int r = 0; r < 4; ++r) mx[r] = fmaxf(acc[mf][2*g][r], acc[mf][2*g+1][r]);
        #pragma unroll
        for (int m = 1; m <= 8; m <<= 1)
          #pragma unroll
          for (int r = 0; r < 4; ++r) mx[r] = fmaxf(mx[r], __shfl_xor(mx[r], m, 64));
        if (ll == 0) {
          int s = ((colbase + g*32) >> 5) & (HS-1);
          int chg = blockIdx.y*128 + ch0;
          #pragma unroll
          for (int r = 0; r < 4; ++r)
            pool[(((size_t)(b*256 + chg + r)) << 10) + s] = mx[r];
        }
      }
    }
    float sv[4] = {0,0,0,0}, qv[4] = {0,0,0,0};
    #pragma unroll
    for (int nf = 0; nf < 4; ++nf)
      #pragma unroll
      for (int r = 0; r < 4; ++r) { float v = acc[mf][nf][r]; sv[r] += v; qv[r] += v*v; }
    #pragma unroll
    for (int m = 1; m <= 8; m <<= 1)
      #pragma unroll
      for (int r = 0; r < 4; ++r) { sv[r] += __shfl_xor(sv[r], m, 64); qv[r] += __shfl_xor(qv[r], m, 64); }
    if (ll == 0) {
      #pragma unroll
      for (int r = 0; r < 4; ++r) { atomicAdd(&bsum[ch0+r], sv[r]); atomicAdd(&bsq[ch0+r], qv[r]); }
    }
  }
  __syncthreads();
  // atomic-free: one coalesced 1KB partial store per block
  float pv = (tid < 128) ? bsum[tid] : bsq[tid - 128];
  pstat[((size_t)(blockIdx.y * gridDim.x + blockIdx.x)) * 256 + tid] = pv;
}

// =====================================================================
// BN finalize: block-per-channel reduction of per-block partials
// =====================================================================
__global__ __launch_bounds__(256) void fin_kernel(
    const float* __restrict__ pstat, int nblk,
    const float* __restrict__ g, const float* __restrict__ be,
    _Float16* __restrict__ Ah, _Float16* __restrict__ Bh,
    float* __restrict__ Af, float* __restrict__ Bf)
{
  const int ch = blockIdx.x;           // 0..C-1
  const int y = ch >> 7, c = ch & 127; // y=0 for C=128
  const float* base = pstat + (size_t)y * nblk * 256;
  const int t = threadIdx.x;
  float s = 0.0f, q = 0.0f;
  for (int k = t; k < nblk; k += 256) {
    s += base[(size_t)k*256 + c];
    q += base[(size_t)k*256 + 128 + c];
  }
  #pragma unroll
  for (int m = 1; m < 64; m <<= 1) { s += __shfl_xor(s, m, 64); q += __shfl_xor(q, m, 64); }
  __shared__ float ss[4], sq[4];
  if ((t & 63) == 0) { ss[t >> 6] = s; sq[t >> 6] = q; }
  __syncthreads();
  if (t == 0) {
    s = ((ss[0] + ss[1]) + (ss[2] + ss[3]));
    q = ((sq[0] + sq[1]) + (sq[2] + sq[3]));
    float mean = s * (1.0f/524288.0f);
    float var  = q * (1.0f/524288.0f) - mean*mean;
    float a  = g[ch] * rsqrtf(var + 1e-5f);
    float bb = be[ch] - mean*a;
    if (Ah) { Ah[ch] = (_Float16)a; Bh[ch] = (_Float16)bb; }
    else    { Af[ch] = a; Bf[ch] = bb; }
  }
}

// =====================================================================
// Final in-place affine+relu on pooled output (bn3)
// =====================================================================
__global__ __launch_bounds__(256) void final_affine(float* __restrict__ outp,
                                                    const float* __restrict__ Af,
                                                    const float* __restrict__ Bf)
{
  int i = blockIdx.x*256 + threadIdx.x;
  float4 v = ((float4*)outp)[i];
  int ch = ((i << 2) >> 10) & 255;
  float a = Af[ch], bb = Bf[ch];
  v.x = fmaxf(v.x*a + bb, 0.0f);
  v.y = fmaxf(v.y*a + bb, 0.0f);
  v.z = fmaxf(v.z*a + bb, 0.0f);
  v.w = fmaxf(v.w*a + bb, 0.0f);
  ((float4*)outp)[i] = v;
}

// =====================================================================
extern "C" void kernel_launch(void* const* d_in, const int* in_sizes, int n_in,
                              void* d_out, int out_size, void* d_ws, size_t ws_size,
                              hipStream_t stream) {
  const float* xyz      = (const float*)d_in[0];
  const float* features = (const float*)d_in[1];
  const float* w1  = (const float*)d_in[2];
  const float* g1  = (const float*)d_in[3];
  const float* b1v = (const float*)d_in[4];
  const float* w2  = (const float*)d_in[5];
  const float* g2  = (const float*)d_in[6];
  const float* b2v = (const float*)d_in[7];
  const float* w3  = (const float*)d_in[8];
  const float* g3  = (const float*)d_in[9];
  const float* b3v = (const float*)d_in[10];
  float* out = (float*)d_out;
  char* ws = (char*)d_ws;

  _Float16* A1h = (_Float16*)(ws + WS_BN);
  _Float16* B1h = A1h + 128;
  _Float16* A2h = A1h + 256;
  _Float16* B2h = A1h + 384;
  float* a3f = (float*)(ws + WS_BN + 1024);
  float* b3f = a3f + 256;
  _Float16* a1h = (_Float16*)(ws + WS_A1H);
  _Float16* a2h = (_Float16*)(ws + WS_A2H);
  _Float16* a3h = (_Float16*)(ws + WS_A3H);
  float4* xyzpp = (float4*)(ws + WS_XYZPP);
  int* gidx = (int*)(ws + WS_GIDX);
  _Float16* featt = (_Float16*)(ws + WS_FEATT);
  u64* keybuf = (u64*)(ws + WS_Y1);
  _Float16* y1 = (_Float16*)(ws + WS_Y1);
  _Float16* y2 = y1;   // conv2 output overwrites y1 in place

  // stat partial buffers (all in regions dead at the time of use):
  float* p1 = out + 49152;                         // d_out tail, overwritten later by pool
  float* p2 = (float*)(ws + WS_FEATT);             // featt dead after conv1
  float* p3 = (float*)(ws + WS_FEATT + 4194304);   // 4MB further in, dead region

  head_kernel<<<1568, 256, 0, stream>>>(xyz, features, w1, w2, w3,
                                        a1h, a2h, a3h, featt, xyzpp, out);
  knn_p1<<<2048, 64, 0, stream>>>(out, xyzpp, keybuf);
  knn_p2<<<256, 64, 0, stream>>>(keybuf, gidx);

  conv_kernel<1><<<2048, 256, 0, stream>>>(a1h, featt, gidx, xyzpp, out,
                                           nullptr, nullptr, y1, p1, nullptr);
  fin_kernel<<<128, 256, 0, stream>>>(p1, 2048, g1, b1v, A1h, B1h, nullptr, nullptr);

  conv_kernel<2><<<2048, 256, 0, stream>>>(a2h, y1, nullptr, nullptr, nullptr,
                                           A1h, B1h, y2, p2, nullptr);
  fin_kernel<<<128, 256, 0, stream>>>(p2, 2048, g2, b2v, A2h, B2h, nullptr, nullptr);

  conv_kernel<3><<<dim3(2048, 2), 256, 0, stream>>>(a3h, y2, nullptr, nullptr, nullptr,
                                                    A2h, B2h, nullptr, p3, out + 49152);
  fin_kernel<<<256, 256, 0, stream>>>(p3, 2048, g3, b3v, nullptr, nullptr, a3f, b3f);

  final_affine<<<4096, 256, 0, stream>>>(out + 49152, a3f, b3f);
}